// Round 1
// baseline (70839.648 us; speedup 1.0000x reference)
//
#include <hip/hip_runtime.h>
#include <math.h>

#define BATCH 512
#define TMAX  200
#define KIN   256     // x / emission dim
#define HID   1024
#define MLPH  1024

// ---------- math helpers (precise this round; A/B fast variants later) ----------
__device__ __forceinline__ float sig_(float x)  { return 1.0f / (1.0f + expf(-x)); }
__device__ __forceinline__ float tanh_(float x) { return tanhf(x); }

// ---------- packed-sequence offsets ----------
__global__ void k_setup(const int* __restrict__ lengths, int* __restrict__ bs, int* __restrict__ off) {
    __shared__ int sbs[TMAX];
    int t = threadIdx.x;
    if (t < TMAX) {
        int c = 0;
        for (int b = 0; b < BATCH; ++b) c += (lengths[b] > t) ? 1 : 0;
        sbs[t] = c;
    }
    __syncthreads();
    if (t == 0) {
        int acc = 0;
        for (int i = 0; i < TMAX; ++i) { bs[i] = sbs[i]; off[i] = acc; acc += sbs[i]; }
    }
}

// ---------- phase A: x_t -> gi -> h (GRU, h_prev=0), scatter h ----------
// grid (16,8) = (HID/64, BATCH/64), 256 threads, thread tile 4x4, 3 accum sets
__global__ __launch_bounds__(256) void k_phaseA(
    const float* __restrict__ pbuf,   // [512][512] = p1|p2 of previous step
    const float* __restrict__ eps,    // [200][512][256]
    const float* __restrict__ W_ih,   // [3072][256]
    const float* __restrict__ b_ih,   // [3072]
    const float* __restrict__ b_hh,   // [3072]
    float* __restrict__ hbuf,         // [512][1024]
    float* __restrict__ hout,         // packed [N][1024]
    const int* __restrict__ bs, const int* __restrict__ off,
    int t)
{
    const int BM = 64, BN = 64, BK = 32;
    __shared__ float As[BK][BM + 4];
    __shared__ float Wr[BK][BN + 4];
    __shared__ float Wz[BK][BN + 4];
    __shared__ float Wn[BK][BN + 4];

    const int tid = threadIdx.x;
    const int tx = tid & 15, ty = tid >> 4;
    const int n0 = blockIdx.x * BN;
    const int m0 = blockIdx.y * BM;

    float accR[4][4] = {{0}}, accZ[4][4] = {{0}}, accN[4][4] = {{0}};

    if (t > 0) {
        const float* __restrict__ epst = eps + (size_t)(t - 1) * (BATCH * KIN);
        for (int k0 = 0; k0 < KIN; k0 += BK) {
            // stage x tile: x = p1 + exp(0.5*p2)*eps[t-1]
            for (int i = tid; i < BM * BK; i += 256) {
                int m = i >> 5, kk = i & 31;
                int b = m0 + m, k = k0 + kk;
                float p1 = pbuf[b * 512 + k];
                float p2 = pbuf[b * 512 + 256 + k];
                float e  = epst[b * KIN + k];
                As[kk][m] = p1 + expf(0.5f * p2) * e;
            }
            // stage weight tiles (r,z,n chunks of W_ih)
            for (int i = tid; i < BN * BK; i += 256) {
                int n = i >> 5, kk = i & 31;
                int k = k0 + kk;
                Wr[kk][n] = W_ih[(size_t)(n0 + n) * KIN + k];
                Wz[kk][n] = W_ih[(size_t)(HID + n0 + n) * KIN + k];
                Wn[kk][n] = W_ih[(size_t)(2 * HID + n0 + n) * KIN + k];
            }
            __syncthreads();
            #pragma unroll
            for (int kk = 0; kk < BK; ++kk) {
                const float4 a4 = *(const float4*)&As[kk][ty * 4];
                const float4 r4 = *(const float4*)&Wr[kk][tx * 4];
                const float4 z4 = *(const float4*)&Wz[kk][tx * 4];
                const float4 n4 = *(const float4*)&Wn[kk][tx * 4];
                const float av[4] = {a4.x, a4.y, a4.z, a4.w};
                const float rv[4] = {r4.x, r4.y, r4.z, r4.w};
                const float zv[4] = {z4.x, z4.y, z4.z, z4.w};
                const float nv[4] = {n4.x, n4.y, n4.z, n4.w};
                #pragma unroll
                for (int i = 0; i < 4; ++i)
                    #pragma unroll
                    for (int j = 0; j < 4; ++j) {
                        accR[i][j] = fmaf(av[i], rv[j], accR[i][j]);
                        accZ[i][j] = fmaf(av[i], zv[j], accZ[i][j]);
                        accN[i][j] = fmaf(av[i], nv[j], accN[i][j]);
                    }
            }
            __syncthreads();
        }
    }
    // epilogue: GRU elementwise (h_prev = 0), write h, scatter packed h
    const int bsz = bs[t], ofs = off[t];
    #pragma unroll
    for (int i = 0; i < 4; ++i) {
        const int b = m0 + ty * 4 + i;
        #pragma unroll
        for (int j = 0; j < 4; ++j) {
            const int jj = n0 + tx * 4 + j;
            float r = sig_(accR[i][j] + b_ih[jj]           + b_hh[jj]);
            float z = sig_(accZ[i][j] + b_ih[HID + jj]     + b_hh[HID + jj]);
            float n = tanh_(accN[i][j] + b_ih[2 * HID + jj] + r * b_hh[2 * HID + jj]);
            float h = (1.0f - z) * n;
            hbuf[(size_t)b * HID + jj] = h;
            if (b < bsz) hout[(size_t)(ofs + b) * HID + jj] = h;
        }
    }
}

// ---------- phase B: ha = tanh(h @ {W1a|W2a}^T + b) ----------
// grid (32,8) = (2048/64, 512/64), 256 threads, thread tile 4x4
__global__ __launch_bounds__(256) void k_phaseB(
    const float* __restrict__ hbuf,   // [512][1024]
    const float* __restrict__ W1a, const float* __restrict__ b1a,
    const float* __restrict__ W2a, const float* __restrict__ b2a,
    float* __restrict__ habuf)        // [512][2048]  (left: mlp1, right: mlp2)
{
    const int BM = 64, BN = 64, BK = 32;
    __shared__ float As[BK][BM + 4];
    __shared__ float Ws[BK][BN + 4];
    const int tid = threadIdx.x;
    const int tx = tid & 15, ty = tid >> 4;
    const int n0 = blockIdx.x * BN;
    const int m0 = blockIdx.y * BM;

    const float* __restrict__ W;
    const float* __restrict__ bias;
    int nrel;
    if (n0 < HID) { W = W1a; bias = b1a; nrel = n0; }
    else          { W = W2a; bias = b2a; nrel = n0 - HID; }

    float acc[4][4] = {{0}};
    for (int k0 = 0; k0 < HID; k0 += BK) {
        for (int i = tid; i < BM * BK; i += 256) {
            int m = i >> 5, kk = i & 31;
            As[kk][m] = hbuf[(size_t)(m0 + m) * HID + k0 + kk];
        }
        for (int i = tid; i < BN * BK; i += 256) {
            int n = i >> 5, kk = i & 31;
            Ws[kk][n] = W[(size_t)(nrel + n) * HID + k0 + kk];
        }
        __syncthreads();
        #pragma unroll
        for (int kk = 0; kk < BK; ++kk) {
            const float4 a4 = *(const float4*)&As[kk][ty * 4];
            const float4 w4 = *(const float4*)&Ws[kk][tx * 4];
            const float av[4] = {a4.x, a4.y, a4.z, a4.w};
            const float wv[4] = {w4.x, w4.y, w4.z, w4.w};
            #pragma unroll
            for (int i = 0; i < 4; ++i)
                #pragma unroll
                for (int j = 0; j < 4; ++j)
                    acc[i][j] = fmaf(av[i], wv[j], acc[i][j]);
        }
        __syncthreads();
    }
    #pragma unroll
    for (int i = 0; i < 4; ++i) {
        const int b = m0 + ty * 4 + i;
        #pragma unroll
        for (int j = 0; j < 4; ++j) {
            const int n = n0 + tx * 4 + j;
            habuf[(size_t)b * 2048 + n] = tanh_(acc[i][j] + bias[nrel + tx * 4 + j]);
        }
    }
}

// ---------- phase C: p1/p2 = ha @ {W1b|W2b}^T + b; scatter p1,p2; write pbuf ----------
// grid (16,16): N-space 512 unified (n<256 -> p1, else p2). BM=BN=32, thread 2x2.
__global__ __launch_bounds__(256) void k_phaseC(
    const float* __restrict__ habuf,  // [512][2048]
    const float* __restrict__ W1b, const float* __restrict__ b1b,
    const float* __restrict__ W2b, const float* __restrict__ b2b,
    float* __restrict__ pbuf,         // [512][512]
    float* __restrict__ out_p1, float* __restrict__ out_p2,
    const int* __restrict__ bs, const int* __restrict__ off, int t)
{
    const int BM = 32, BN = 32, BK = 32;
    __shared__ float As[BK][BM + 4];
    __shared__ float Ws[BK][BN + 4];
    const int tid = threadIdx.x;
    const int tx = tid & 15, ty = tid >> 4;
    const int n0 = blockIdx.x * BN;
    const int m0 = blockIdx.y * BM;

    const float* __restrict__ W;
    const float* __restrict__ bias;
    int nrel, acol;
    if (n0 < 256) { W = W1b; bias = b1b; nrel = n0;       acol = 0;   }
    else          { W = W2b; bias = b2b; nrel = n0 - 256; acol = HID; }

    float acc[2][2] = {{0}};
    for (int k0 = 0; k0 < MLPH; k0 += BK) {
        for (int i = tid; i < BM * BK; i += 256) {
            int m = i >> 5, kk = i & 31;
            As[kk][m] = habuf[(size_t)(m0 + m) * 2048 + acol + k0 + kk];
        }
        for (int i = tid; i < BN * BK; i += 256) {
            int n = i >> 5, kk = i & 31;
            Ws[kk][n] = W[(size_t)(nrel + n) * MLPH + k0 + kk];
        }
        __syncthreads();
        #pragma unroll
        for (int kk = 0; kk < BK; ++kk) {
            const float2 a2 = *(const float2*)&As[kk][ty * 2];
            const float2 w2 = *(const float2*)&Ws[kk][tx * 2];
            acc[0][0] = fmaf(a2.x, w2.x, acc[0][0]);
            acc[0][1] = fmaf(a2.x, w2.y, acc[0][1]);
            acc[1][0] = fmaf(a2.y, w2.x, acc[1][0]);
            acc[1][1] = fmaf(a2.y, w2.y, acc[1][1]);
        }
        __syncthreads();
    }
    const int bsz = bs[t], ofs = off[t];
    #pragma unroll
    for (int i = 0; i < 2; ++i) {
        const int b = m0 + ty * 2 + i;
        #pragma unroll
        for (int j = 0; j < 2; ++j) {
            const int ng = n0 + tx * 2 + j;
            const float v = acc[i][j] + bias[nrel + tx * 2 + j];
            pbuf[(size_t)b * 512 + ng] = v;
            if (b < bsz) {
                if (ng < 256) out_p1[(size_t)(ofs + b) * 256 + ng] = v;
                else          out_p2[(size_t)(ofs + b) * 256 + (ng - 256)] = v;
            }
        }
    }
}

// ---------- launcher ----------
extern "C" void kernel_launch(void* const* d_in, const int* in_sizes, int n_in,
                              void* d_out, int out_size, void* d_ws, size_t ws_size,
                              hipStream_t stream)
{
    // input order per setup_inputs(): features, lengths, eps, W_f2h, b_f2h,
    // W_ih, b_ih, W_hh, b_hh, W1a, b1a, W1b, b1b, W2a, b2a, W2b, b2b, W_off, b_off
    const int*   lengths = (const int*)  d_in[1];
    const float* eps     = (const float*)d_in[2];
    const float* W_ih    = (const float*)d_in[5];
    const float* b_ih    = (const float*)d_in[6];
    const float* b_hh    = (const float*)d_in[8];
    const float* W1a     = (const float*)d_in[9];
    const float* b1a     = (const float*)d_in[10];
    const float* W1b     = (const float*)d_in[11];
    const float* b1b     = (const float*)d_in[12];
    const float* W2a     = (const float*)d_in[13];
    const float* b2a     = (const float*)d_in[14];
    const float* W2b     = (const float*)d_in[15];
    const float* b2b     = (const float*)d_in[16];

    float* out = (float*)d_out;
    const size_t N = (size_t)out_size / 1536;   // sum(lengths)
    float* out_p1 = out;                         // [N][256]
    float* out_p2 = out + N * 256;               // [N][256]
    float* out_h  = out + N * 512;               // [N][1024]

    char* ws = (char*)d_ws;
    int* bs  = (int*)ws;                 // 200 ints
    int* off = (int*)(ws + 1024);        // 200 ints
    float* pbuf  = (float*)(ws + 4096);  // [512][512]
    float* hbuf  = pbuf + 512 * 512;     // [512][1024]
    float* habuf = hbuf + 512 * 1024;    // [512][2048]
    // total ~7.4 MB of d_ws

    k_setup<<<1, 256, 0, stream>>>(lengths, bs, off);

    for (int t = 0; t < TMAX; ++t) {
        k_phaseA<<<dim3(16, 8), 256, 0, stream>>>(pbuf, eps, W_ih, b_ih, b_hh,
                                                  hbuf, out_h, bs, off, t);
        k_phaseB<<<dim3(32, 8), 256, 0, stream>>>(hbuf, W1a, b1a, W2a, b2a, habuf);
        k_phaseC<<<dim3(16, 16), 256, 0, stream>>>(habuf, W1b, b1b, W2b, b2b,
                                                   pbuf, out_p1, out_p2, bs, off, t);
    }
}